// Round 11
// baseline (452.010 us; speedup 1.0000x reference)
//
#include <hip/hip_runtime.h>

#define NB   4
#define CH   256
#define CQK  32
#define NPOS 4096
#define KT   64
#define QT   64
#define LOG2E 1.4426950408889634f
#define THR2  10.0f   // defer-rescale threshold in log2 units (P <= 2^10)

typedef __attribute__((ext_vector_type(8))) short bf16x8;
typedef __attribute__((ext_vector_type(4))) float f32x4;
typedef unsigned short u16;
typedef unsigned int   u32;

static __device__ __forceinline__ u16 f2bf(float x) {
    union { float f; u32 u; } c; c.f = x;
    u32 u = c.u + 0x7FFFu + ((c.u >> 16) & 1u);
    return (u16)(u >> 16);
}
static __device__ __forceinline__ u32 pack2(float a, float b) {
    return (u32)f2bf(a) | ((u32)f2bf(b) << 16);
}
static __device__ __forceinline__ u32 cvtpk(float a, float b) {
    u32 r;
    asm("v_cvt_pk_bf16_f32 %0, %1, %2" : "=v"(r) : "v"(a), "v"(b));
    return r;
}
static __device__ __forceinline__ float exp2raw(float x) {
    float r;
    asm("v_exp_f32 %0, %1" : "=v"(r) : "v"(x));
    return r;
}
// keep loads live without cost (rule #17)
static __device__ __forceinline__ void sinkv(const bf16x8& x) {
    uint4 u; __builtin_memcpy(&u, &x, 16);
    asm volatile("" :: "v"(u.x), "v"(u.y), "v"(u.z), "v"(u.w));
}

// ---------------------------------------------------------------------------
// W concat + bf16 convert (unchanged).
// ---------------------------------------------------------------------------
__global__ __launch_bounds__(256) void wcvt_kernel(
    const float* __restrict__ wq, const float* __restrict__ bq,
    const float* __restrict__ wk, const float* __restrict__ bk,
    const float* __restrict__ wv, const float* __restrict__ bv,
    u16* __restrict__ wb, float* __restrict__ bb)
{
    int idx = blockIdx.x * 256 + threadIdx.x;
    int e0 = idx * 4;
    const float* src; int off;
    if (e0 < 32 * 256)      { src = wq; off = e0; }
    else if (e0 < 64 * 256) { src = wk; off = e0 - 32 * 256; }
    else                    { src = wv; off = e0 - 64 * 256; }
    float4 v4 = *(const float4*)(src + off);
    *(uint2*)(wb + e0) = make_uint2(pack2(v4.x, v4.y), pack2(v4.z, v4.w));
    if (idx < 320) {
        float b = idx < 32 ? bq[idx] : (idx < 64 ? bk[idx - 32] : bv[idx - 64]);
        bb[idx] = b;
    }
}

// ---------------------------------------------------------------------------
// MFMA QKV projection (unchanged; Q pre-scaled by log2e).
// ---------------------------------------------------------------------------
__global__ __launch_bounds__(256, 1) void qkv_proj_kernel(
    const float* __restrict__ x, const u16* __restrict__ wb, const float* __restrict__ bb,
    u16* __restrict__ qo, u16* __restrict__ ko, u16* __restrict__ vo)
{
    __shared__ u16 ldsx[32][264];
    const int t  = threadIdx.x;
    const int b  = blockIdx.x >> 7;
    const int n0 = (blockIdx.x & 127) * 32;
    const float* xb = x + (size_t)b * CH * NPOS;

    #pragma unroll
    for (int it = 0; it < 4; ++it) {
        int idx = it * 256 + t;
        int cp = idx >> 3;
        int n4 = (idx & 7) * 4;
        int c  = cp * 2;
        float4 a = *(const float4*)(xb + (size_t)c * NPOS + n0 + n4);
        float4 d = *(const float4*)(xb + (size_t)(c + 1) * NPOS + n0 + n4);
        #pragma unroll
        for (int i = 0; i < 4; ++i) {
            int n = n4 + i;
            u32 pv = pack2(((const float*)&a)[i], ((const float*)&d)[i]);
            *(u32*)((char*)ldsx + n * 528 + ((c * 2) ^ ((n & 7) << 4))) = pv;
        }
    }
    __syncthreads();

    const int w = t >> 6, lane = t & 63, g8 = lane >> 4, l16 = lane & 15;

    bf16x8 bf[2][8];
    #pragma unroll
    for (int ns = 0; ns < 2; ++ns) {
        int n = ns * 16 + l16;
        const char* rowp = (const char*)ldsx + n * 528;
        int swz = (n & 7) << 4;
        #pragma unroll
        for (int ks = 0; ks < 8; ++ks)
            bf[ns][ks] = *(const bf16x8*)(rowp + ((ks * 64 + g8 * 16) ^ swz));
    }

    u16* qdst = qo + (size_t)b * NPOS * CQK;
    u16* kdst = ko + (size_t)b * NPOS * CQK;
    u16* vdst = vo + (size_t)b * CH * NPOS;

    bf16x8 afA[8], afB[8];
    #pragma unroll
    for (int ks = 0; ks < 8; ++ks)
        afA[ks] = *(const bf16x8*)(wb + (w * 5 * 16 + l16) * 256 + ks * 32 + g8 * 8);

    #pragma unroll
    for (int j = 0; j < 5; ++j) {
        int ot = w * 5 + j;
        bf16x8* afc = (j & 1) ? afB : afA;
        bf16x8* afn = (j & 1) ? afA : afB;
        if (j + 1 < 5) {
            int otn = ot + 1;
            #pragma unroll
            for (int ks = 0; ks < 8; ++ks)
                afn[ks] = *(const bf16x8*)(wb + (otn * 16 + l16) * 256 + ks * 32 + g8 * 8);
        }
        f32x4 acc[2];
        acc[0] = (f32x4){0.f, 0.f, 0.f, 0.f};
        acc[1] = (f32x4){0.f, 0.f, 0.f, 0.f};
        #pragma unroll
        for (int ks = 0; ks < 8; ++ks) {
            acc[0] = __builtin_amdgcn_mfma_f32_16x16x32_bf16(afc[ks], bf[0][ks], acc[0], 0, 0, 0);
            acc[1] = __builtin_amdgcn_mfma_f32_16x16x32_bf16(afc[ks], bf[1][ks], acc[1], 0, 0, 0);
        }
        float4 bias = *(const float4*)(bb + ot * 16 + g8 * 4);

        if (ot < 4) {
            u16* dst = (ot < 2 ? qdst : kdst);
            float scl = (ot < 2) ? LOG2E : 1.0f;
            int ob = (ot & 1) * 16 + g8 * 4;
            #pragma unroll
            for (int ns = 0; ns < 2; ++ns) {
                int n = n0 + ns * 16 + l16;
                u32 lo = pack2((acc[ns][0] + bias.x) * scl, (acc[ns][1] + bias.y) * scl);
                u32 hi = pack2((acc[ns][2] + bias.z) * scl, (acc[ns][3] + bias.w) * scl);
                *(uint2*)(dst + (size_t)n * CQK + ob) = make_uint2(lo, hi);
            }
        } else {
            int orow = (ot - 4) * 16 + g8 * 4;
            const float* bp = (const float*)&bias;
            #pragma unroll
            for (int r = 0; r < 4; ++r)
                #pragma unroll
                for (int ns = 0; ns < 2; ++ns)
                    vdst[(size_t)(orow + r) * NPOS + n0 + ns * 16 + l16] =
                        f2bf(acc[ns][r] + bp[r]);
        }
    }
}

// ---------------------------------------------------------------------------
// Production attn (R10, unchanged): key-split P/C, KT=64, grid 512, merge.
// ---------------------------------------------------------------------------
#define P_OFF   0        // 2 bufs x 4 strips x 16 q x 128B = 16384
#define SC_OFF  16384    // 2 x 64 f32 = 512
#define FL_OFF  16896    // 2 x 16B = 32
#define LL_OFF  16928    // 64 f32 = 256
#define SMEMSZ  17184

template<bool SPLIT>
__global__ __launch_bounds__(512, 2) void attn_kernel(
    const u16* __restrict__ q, const u16* __restrict__ k, const u16* __restrict__ v,
    const float* __restrict__ input, const float* __restrict__ gamma,
    float* __restrict__ out, float* __restrict__ pO, float* __restrict__ pml)
{
    __shared__ __align__(16) char smem[SMEMSZ];
    const int t = threadIdx.x;
    const int w = t >> 6;
    const int lane = t & 63;
    const int g8 = lane >> 4;
    const int l16 = lane & 15;

    constexpr int W = SPLIT ? 32 : 64;
    const int bid = blockIdx.x;
    const int h = SPLIT ? (bid >> 8) : 0;
    const int lb = bid & 255;
    const int b = (lb >> 1) & 3;
    const int tile = ((lb >> 3) << 1) | (lb & 1);
    const int s = b * 64 + tile;
    const int i0 = tile * QT;
    const int kbase = h * (NPOS / 2);

    const u16* kb = k + (size_t)b * NPOS * CQK;
    const u16* vb = v + (size_t)b * CH * NPOS;

    if (w < 4) {
        const int strip = w;
        const u16* qb = q + (size_t)b * NPOS * CQK;
        bf16x8 qf = *(const bf16x8*)(qb + (size_t)(i0 + strip * 16 + l16) * CQK + g8 * 8);
        float mrun = -__builtin_inff(), lrun = 0.f;

        bf16x8 kc[4];
        #pragma unroll
        for (int nt = 0; nt < 4; ++nt)
            kc[nt] = *(const bf16x8*)(kb + (size_t)(kbase + nt * 16 + l16) * CQK + g8 * 8);

        auto pbody = [&](int c) {
            f32x4 z = {0.f, 0.f, 0.f, 0.f};
            f32x4 sS[4];
            #pragma unroll
            for (int nt = 0; nt < 4; ++nt)
                sS[nt] = __builtin_amdgcn_mfma_f32_16x16x32_bf16(kc[nt], qf, z, 0, 0, 0);
            {
                int j0n = kbase + ((c + 1) & (W - 1)) * KT;
                #pragma unroll
                for (int nt = 0; nt < 4; ++nt)
                    kc[nt] = *(const bf16x8*)(kb + (size_t)(j0n + nt * 16 + l16) * CQK + g8 * 8);
            }
            float mx4[4];
            #pragma unroll
            for (int nt = 0; nt < 4; ++nt)
                mx4[nt] = fmaxf(fmaxf(sS[nt][0], sS[nt][1]), fmaxf(sS[nt][2], sS[nt][3]));
            float lmax = fmaxf(fmaxf(mx4[0], mx4[1]), fmaxf(mx4[2], mx4[3]));

            const int buf = c & 1;
            float sc = 1.0f;
            u32 flagval = 0u;
            if (__any(lmax > mrun + THR2)) {
                float mxx = fmaxf(lmax, __shfl_xor(lmax, 16));
                mxx = fmaxf(mxx, __shfl_xor(mxx, 32));
                mxx = fmaxf(mxx, mrun);
                sc = exp2raw(mrun - mxx);
                mrun = mxx;
                lrun *= sc;
                flagval = 1u;
            }
            if (g8 == 0)
                *(float*)(smem + SC_OFF + buf * 256 + (strip * 16 + l16) * 4) = sc;

            float ls = 0.f;
            char* pb = smem + P_OFF + buf * 8192 + strip * 2048 + l16 * 128;
            int swz = (l16 & 7) << 4;
            #pragma unroll
            for (int nt = 0; nt < 4; ++nt) {
                float a0 = exp2raw(sS[nt][0] - mrun);
                float a1 = exp2raw(sS[nt][1] - mrun);
                float a2 = exp2raw(sS[nt][2] - mrun);
                float a3 = exp2raw(sS[nt][3] - mrun);
                ls += (a0 + a1) + (a2 + a3);
                *(uint2*)(pb + ((nt * 32 + g8 * 8) ^ swz)) =
                    make_uint2(cvtpk(a0, a1), cvtpk(a2, a3));
            }
            lrun += ls;
            if (lane == 0)
                *(u32*)(smem + FL_OFF + buf * 16 + strip * 4) = flagval;
            asm volatile("s_waitcnt lgkmcnt(0)" ::: "memory");
        };

        pbody(0);
        for (int jc = 0; jc < W; jc += 2) {
            __builtin_amdgcn_s_barrier();
            asm volatile("" ::: "memory");
            pbody(jc + 1);
            __builtin_amdgcn_s_barrier();
            asm volatile("" ::: "memory");
            if (jc + 2 < W) pbody(jc + 2);
        }
        lrun += __shfl_xor(lrun, 16);
        lrun += __shfl_xor(lrun, 32);
        if (SPLIT) {
            if (g8 == 0) {
                float2 ml = make_float2(mrun, lrun);
                ((float2*)pml)[(size_t)(h * 256 + s) * 64 + strip * 16 + l16] = ml;
            }
        } else {
            if (g8 == 0)
                *(float*)(smem + LL_OFF + (strip * 16 + l16) * 4) = lrun;
            __syncthreads();
        }
    } else {
        const int ch0 = (w - 4) * 64;
        bf16x8 vc[8];
        #pragma unroll
        for (int ct = 0; ct < 4; ++ct)
            #pragma unroll
            for (int ks = 0; ks < 2; ++ks)
                vc[ct * 2 + ks] = *(const bf16x8*)(vb + (size_t)(ch0 + ct * 16 + l16) * NPOS
                                                   + kbase + ks * 32 + g8 * 8);
        f32x4 acc[4][4];
        #pragma unroll
        for (int mt = 0; mt < 4; ++mt)
            #pragma unroll
            for (int ct = 0; ct < 4; ++ct)
                acc[mt][ct] = (f32x4){0.f, 0.f, 0.f, 0.f};

        auto cbody = [&](int jc) {
            const int buf = jc & 1;
            __builtin_amdgcn_s_barrier();
            asm volatile("" ::: "memory");
            __builtin_amdgcn_sched_barrier(0);
            uint4 fl = *(const uint4*)(smem + FL_OFF + buf * 16);
            if (fl.x | fl.y | fl.z | fl.w) {
                #pragma unroll
                for (int mt = 0; mt < 4; ++mt) {
                    f32x4 ss = *(const f32x4*)(smem + SC_OFF + buf * 256 + (mt * 16 + g8 * 4) * 4);
                    #pragma unroll
                    for (int ct = 0; ct < 4; ++ct) acc[mt][ct] *= ss;
                }
            }
            int swz = (l16 & 7) << 4;
            __builtin_amdgcn_s_setprio(1);
            #pragma unroll
            for (int mt = 0; mt < 4; ++mt) {
                const char* pb = smem + P_OFF + buf * 8192 + mt * 2048 + l16 * 128;
                bf16x8 pa0 = *(const bf16x8*)(pb + ((g8 * 16) ^ swz));
                bf16x8 pa1 = *(const bf16x8*)(pb + ((64 + g8 * 16) ^ swz));
                #pragma unroll
                for (int ct = 0; ct < 4; ++ct) {
                    acc[mt][ct] = __builtin_amdgcn_mfma_f32_16x16x32_bf16(pa0, vc[ct * 2 + 0], acc[mt][ct], 0, 0, 0);
                    acc[mt][ct] = __builtin_amdgcn_mfma_f32_16x16x32_bf16(pa1, vc[ct * 2 + 1], acc[mt][ct], 0, 0, 0);
                }
            }
            __builtin_amdgcn_s_setprio(0);
            {
                int j0n = kbase + ((jc + 1) & (W - 1)) * KT;
                #pragma unroll
                for (int ct = 0; ct < 4; ++ct)
                    #pragma unroll
                    for (int ks = 0; ks < 2; ++ks)
                        vc[ct * 2 + ks] = *(const bf16x8*)(vb + (size_t)(ch0 + ct * 16 + l16) * NPOS
                                                           + j0n + ks * 32 + g8 * 8);
            }
        };

        for (int jc = 0; jc < W; ++jc) cbody(jc);

        if (SPLIT) {
            float* po = pO + ((size_t)(h * 256 + s) * 256) * 64;
            #pragma unroll
            for (int mt = 0; mt < 4; ++mt)
                #pragma unroll
                for (int ct = 0; ct < 4; ++ct) {
                    int ch = ch0 + ct * 16 + l16;
                    int qi = mt * 16 + g8 * 4;
                    *(f32x4*)(po + (size_t)ch * 64 + qi) = acc[mt][ct];
                }
        } else {
            __syncthreads();
            f32x4 linv[4];
            #pragma unroll
            for (int mt = 0; mt < 4; ++mt) {
                f32x4 lv = *(const f32x4*)(smem + LL_OFF + (mt * 16 + g8 * 4) * 4);
                f32x4 one = {1.f, 1.f, 1.f, 1.f};
                linv[mt] = one / lv;
            }
            const float gmm = gamma[0];
            const float* inb = input + (size_t)b * CH * NPOS;
            float* ob = out + (size_t)b * CH * NPOS;
            #pragma unroll
            for (int mt = 0; mt < 4; ++mt) {
                #pragma unroll
                for (int ct = 0; ct < 4; ++ct) {
                    f32x4 val = acc[mt][ct] * linv[mt];
                    int ch = ch0 + ct * 16 + l16;
                    size_t gi = (size_t)ch * NPOS + i0 + mt * 16 + g8 * 4;
                    float4 in4 = *(const float4*)(inb + gi);
                    float4 r4;
                    r4.x = gmm * val[0] + in4.x;
                    r4.y = gmm * val[1] + in4.y;
                    r4.z = gmm * val[2] + in4.z;
                    r4.w = gmm * val[3] + in4.w;
                    *(float4*)(ob + gi) = r4;
                }
            }
        }
    }
}

// ---------------------------------------------------------------------------
// ABLATION kernel (scratch-only).  Same structure as attn_kernel<true>.
// MODE 2: producer compute removed (const P; barriers/LDS/SC/FL kept).
// MODE 3: consumer MFMA removed (P reads + V loads kept, sunk).
// MODE 4: both (sync + LDS skeleton).
// ---------------------------------------------------------------------------
template<int MODE>
__global__ __launch_bounds__(512, 2) void attn_abl(
    const u16* __restrict__ q, const u16* __restrict__ k, const u16* __restrict__ v,
    float* __restrict__ pO, float* __restrict__ pml)
{
    constexpr bool NOPROD = (MODE == 2) || (MODE == 4);
    constexpr bool NOCONS = (MODE == 3) || (MODE == 4);
    constexpr int W = 32;

    __shared__ __align__(16) char smem[SMEMSZ];
    const int t = threadIdx.x;
    const int w = t >> 6;
    const int lane = t & 63;
    const int g8 = lane >> 4;
    const int l16 = lane & 15;

    const int bid = blockIdx.x;
    const int h = bid >> 8;
    const int lb = bid & 255;
    const int b = (lb >> 1) & 3;
    const int tile = ((lb >> 3) << 1) | (lb & 1);
    const int s = b * 64 + tile;
    const int i0 = tile * QT;
    const int kbase = h * (NPOS / 2);

    const u16* kb = k + (size_t)b * NPOS * CQK;
    const u16* vb = v + (size_t)b * CH * NPOS;

    if (w < 4) {
        const int strip = w;
        bf16x8 qf = {0,0,0,0,0,0,0,0};
        bf16x8 kc[4];
        if constexpr (!NOPROD) {
            const u16* qb = q + (size_t)b * NPOS * CQK;
            qf = *(const bf16x8*)(qb + (size_t)(i0 + strip * 16 + l16) * CQK + g8 * 8);
            #pragma unroll
            for (int nt = 0; nt < 4; ++nt)
                kc[nt] = *(const bf16x8*)(kb + (size_t)(kbase + nt * 16 + l16) * CQK + g8 * 8);
        }
        float mrun = -__builtin_inff(), lrun = 0.f;

        auto pbody = [&](int c) {
            const int buf = c & 1;
            char* pb = smem + P_OFF + buf * 8192 + strip * 2048 + l16 * 128;
            int swz = (l16 & 7) << 4;
            float sc = 1.0f;
            u32 flagval = 0u;
            if constexpr (!NOPROD) {
                f32x4 z = {0.f, 0.f, 0.f, 0.f};
                f32x4 sS[4];
                #pragma unroll
                for (int nt = 0; nt < 4; ++nt)
                    sS[nt] = __builtin_amdgcn_mfma_f32_16x16x32_bf16(kc[nt], qf, z, 0, 0, 0);
                {
                    int j0n = kbase + ((c + 1) & (W - 1)) * KT;
                    #pragma unroll
                    for (int nt = 0; nt < 4; ++nt)
                        kc[nt] = *(const bf16x8*)(kb + (size_t)(j0n + nt * 16 + l16) * CQK + g8 * 8);
                }
                float mx4[4];
                #pragma unroll
                for (int nt = 0; nt < 4; ++nt)
                    mx4[nt] = fmaxf(fmaxf(sS[nt][0], sS[nt][1]), fmaxf(sS[nt][2], sS[nt][3]));
                float lmax = fmaxf(fmaxf(mx4[0], mx4[1]), fmaxf(mx4[2], mx4[3]));
                if (__any(lmax > mrun + THR2)) {
                    float mxx = fmaxf(lmax, __shfl_xor(lmax, 16));
                    mxx = fmaxf(mxx, __shfl_xor(mxx, 32));
                    mxx = fmaxf(mxx, mrun);
                    sc = exp2raw(mrun - mxx);
                    mrun = mxx;
                    lrun *= sc;
                    flagval = 1u;
                }
                float ls = 0.f;
                #pragma unroll
                for (int nt = 0; nt < 4; ++nt) {
                    float a0 = exp2raw(sS[nt][0] - mrun);
                    float a1 = exp2raw(sS[nt][1] - mrun);
                    float a2 = exp2raw(sS[nt][2] - mrun);
                    float a3 = exp2raw(sS[nt][3] - mrun);
                    ls += (a0 + a1) + (a2 + a3);
                    *(uint2*)(pb + ((nt * 32 + g8 * 8) ^ swz)) =
                        make_uint2(cvtpk(a0, a1), cvtpk(a2, a3));
                }
                lrun += ls;
            } else {
                #pragma unroll
                for (int nt = 0; nt < 4; ++nt)
                    *(uint2*)(pb + ((nt * 32 + g8 * 8) ^ swz)) =
                        make_uint2(0x3F803F80u, 0x3F803F80u);   // P = 1.0
            }
            if (g8 == 0)
                *(float*)(smem + SC_OFF + buf * 256 + (strip * 16 + l16) * 4) = sc;
            if (lane == 0)
                *(u32*)(smem + FL_OFF + buf * 16 + strip * 4) = flagval;
            asm volatile("s_waitcnt lgkmcnt(0)" ::: "memory");
        };

        pbody(0);
        for (int jc = 0; jc < W; jc += 2) {
            __builtin_amdgcn_s_barrier();
            asm volatile("" ::: "memory");
            pbody(jc + 1);
            __builtin_amdgcn_s_barrier();
            asm volatile("" ::: "memory");
            if (jc + 2 < W) pbody(jc + 2);
        }
        if (g8 == 0)
            ((float2*)pml)[(size_t)(h * 256 + s) * 64 + strip * 16 + l16] =
                make_float2(mrun, lrun);
    } else {
        const int ch0 = (w - 4) * 64;
        bf16x8 vc[8];
        #pragma unroll
        for (int ct = 0; ct < 4; ++ct)
            #pragma unroll
            for (int ks = 0; ks < 2; ++ks)
                vc[ct * 2 + ks] = *(const bf16x8*)(vb + (size_t)(ch0 + ct * 16 + l16) * NPOS
                                                   + kbase + ks * 32 + g8 * 8);
        f32x4 acc[4][4];
        #pragma unroll
        for (int mt = 0; mt < 4; ++mt)
            #pragma unroll
            for (int ct = 0; ct < 4; ++ct)
                acc[mt][ct] = (f32x4){0.f, 0.f, 0.f, 0.f};

        auto cbody = [&](int jc) {
            const int buf = jc & 1;
            __builtin_amdgcn_s_barrier();
            asm volatile("" ::: "memory");
            __builtin_amdgcn_sched_barrier(0);
            uint4 fl = *(const uint4*)(smem + FL_OFF + buf * 16);
            if (fl.x | fl.y | fl.z | fl.w) {
                #pragma unroll
                for (int mt = 0; mt < 4; ++mt) {
                    f32x4 ss = *(const f32x4*)(smem + SC_OFF + buf * 256 + (mt * 16 + g8 * 4) * 4);
                    #pragma unroll
                    for (int ct = 0; ct < 4; ++ct) acc[mt][ct] *= ss;
                }
            }
            int swz = (l16 & 7) << 4;
            __builtin_amdgcn_s_setprio(1);
            #pragma unroll
            for (int mt = 0; mt < 4; ++mt) {
                const char* pb = smem + P_OFF + buf * 8192 + mt * 2048 + l16 * 128;
                bf16x8 pa0 = *(const bf16x8*)(pb + ((g8 * 16) ^ swz));
                bf16x8 pa1 = *(const bf16x8*)(pb + ((64 + g8 * 16) ^ swz));
                if constexpr (!NOCONS) {
                    #pragma unroll
                    for (int ct = 0; ct < 4; ++ct) {
                        acc[mt][ct] = __builtin_amdgcn_mfma_f32_16x16x32_bf16(pa0, vc[ct * 2 + 0], acc[mt][ct], 0, 0, 0);
                        acc[mt][ct] = __builtin_amdgcn_mfma_f32_16x16x32_bf16(pa1, vc[ct * 2 + 1], acc[mt][ct], 0, 0, 0);
                    }
                } else {
                    sinkv(pa0); sinkv(pa1);
                }
            }
            __builtin_amdgcn_s_setprio(0);
            {
                int j0n = kbase + ((jc + 1) & (W - 1)) * KT;
                #pragma unroll
                for (int ct = 0; ct < 4; ++ct)
                    #pragma unroll
                    for (int ks = 0; ks < 2; ++ks)
                        vc[ct * 2 + ks] = *(const bf16x8*)(vb + (size_t)(ch0 + ct * 16 + l16) * NPOS
                                                           + j0n + ks * 32 + g8 * 8);
                if constexpr (NOCONS) {
                    #pragma unroll
                    for (int i = 0; i < 8; ++i) sinkv(vc[i]);
                }
            }
        };

        for (int jc = 0; jc < W; ++jc) cbody(jc);

        float* po = pO + ((size_t)(h * 256 + s) * 256) * 64;
        #pragma unroll
        for (int mt = 0; mt < 4; ++mt)
            #pragma unroll
            for (int ct = 0; ct < 4; ++ct) {
                int ch = ch0 + ct * 16 + l16;
                int qi = mt * 16 + g8 * 4;
                *(f32x4*)(po + (size_t)ch * 64 + qi) = acc[mt][ct];
            }
    }
}

// ---------------------------------------------------------------------------
// FUSED PROBE (scratch-only): zero barriers.  8 independent waves per block:
// wave = (strip st of 16 q) x (128-ch half).  Per KT=64 window: swapped QK^T
// (4 mfma) -> in-wave softmax -> P via PRIVATE single-buffer LDS (lgkm only)
// -> PV 16 mfma with V in regs from L2 (in-place reload).  W=32 (half keys,
// per-window comparable to the split production kernel).
// ---------------------------------------------------------------------------
__global__ __launch_bounds__(512, 1) void fused_probe(
    const u16* __restrict__ q, const u16* __restrict__ k, const u16* __restrict__ v,
    float* __restrict__ pO)
{
    __shared__ __align__(16) char psm[16384];   // 8 waves x 16 q x 128B
    const int t = threadIdx.x;
    const int w = t >> 6;
    const int lane = t & 63;
    const int g8 = lane >> 4;
    const int l16 = lane & 15;

    const int bid = blockIdx.x;
    const int b = (bid >> 1) & 3;
    const int tile = ((bid >> 3) << 1) | (bid & 1);
    const int i0 = tile * QT;
    const int st = w & 3;
    const int ch0 = (w >> 2) * 128;

    const u16* qb = q + (size_t)b * NPOS * CQK;
    const u16* kb = k + (size_t)b * NPOS * CQK;
    const u16* vb = v + (size_t)b * CH * NPOS;

    bf16x8 qf = *(const bf16x8*)(qb + (size_t)(i0 + st * 16 + l16) * CQK + g8 * 8);
    bf16x8 kc[4];
    #pragma unroll
    for (int nt = 0; nt < 4; ++nt)
        kc[nt] = *(const bf16x8*)(kb + (size_t)(nt * 16 + l16) * CQK + g8 * 8);
    bf16x8 vc[16];
    #pragma unroll
    for (int ct = 0; ct < 8; ++ct)
        #pragma unroll
        for (int ks = 0; ks < 2; ++ks)
            vc[ct * 2 + ks] = *(const bf16x8*)(vb + (size_t)(ch0 + ct * 16 + l16) * NPOS
                                               + ks * 32 + g8 * 8);
    f32x4 acc[8];
    #pragma unroll
    for (int ct = 0; ct < 8; ++ct) acc[ct] = (f32x4){0.f, 0.f, 0.f, 0.f};
    float mrun = -__builtin_inff(), lrun = 0.f;

    char* pw = psm + w * 2048;
    const int swz = (l16 & 7) << 4;

    for (int jc = 0; jc < 32; ++jc) {
        f32x4 z = {0.f, 0.f, 0.f, 0.f};
        f32x4 sS[4];
        #pragma unroll
        for (int nt = 0; nt < 4; ++nt)
            sS[nt] = __builtin_amdgcn_mfma_f32_16x16x32_bf16(kc[nt], qf, z, 0, 0, 0);
        {
            int j0n = ((jc + 1) & 63) * KT;
            #pragma unroll
            for (int nt = 0; nt < 4; ++nt)
                kc[nt] = *(const bf16x8*)(kb + (size_t)(j0n + nt * 16 + l16) * CQK + g8 * 8);
        }
        float mx4[4];
        #pragma unroll
        for (int nt = 0; nt < 4; ++nt)
            mx4[nt] = fmaxf(fmaxf(sS[nt][0], sS[nt][1]), fmaxf(sS[nt][2], sS[nt][3]));
        float lmax = fmaxf(fmaxf(mx4[0], mx4[1]), fmaxf(mx4[2], mx4[3]));
        if (__any(lmax > mrun + THR2)) {        // rare: in-wave rescale
            float mxx = fmaxf(lmax, __shfl_xor(lmax, 16));
            mxx = fmaxf(mxx, __shfl_xor(mxx, 32));
            mxx = fmaxf(mxx, mrun);
            float sc = exp2raw(mrun - mxx);
            mrun = mxx;
            lrun *= sc;
            // acc rows are queries g8*4+r; sc lives by l16 -> 4 bpermutes
            f32x4 sv;
            #pragma unroll
            for (int r = 0; r < 4; ++r) sv[r] = __shfl(sc, g8 * 4 + r);
            #pragma unroll
            for (int ct = 0; ct < 8; ++ct) acc[ct] *= sv;
        }
        float ls = 0.f;
        char* prow = pw + l16 * 128;
        #pragma unroll
        for (int nt = 0; nt < 4; ++nt) {
            float a0 = exp2raw(sS[nt][0] - mrun);
            float a1 = exp2raw(sS[nt][1] - mrun);
            float a2 = exp2raw(sS[nt][2] - mrun);
            float a3 = exp2raw(sS[nt][3] - mrun);
            ls += (a0 + a1) + (a2 + a3);
            *(uint2*)(prow + ((nt * 32 + g8 * 8) ^ swz)) =
                make_uint2(cvtpk(a0, a1), cvtpk(a2, a3));
        }
        lrun += ls;
        asm volatile("s_waitcnt lgkmcnt(0)" ::: "memory");
        bf16x8 pa0 = *(const bf16x8*)(pw + l16 * 128 + ((g8 * 16) ^ swz));
        bf16x8 pa1 = *(const bf16x8*)(pw + l16 * 128 + ((64 + g8 * 16) ^ swz));
        const int j0n = ((jc + 1) & 63) * KT;
        __builtin_amdgcn_s_setprio(1);
        #pragma unroll
        for (int ct = 0; ct < 8; ++ct) {
            acc[ct] = __builtin_amdgcn_mfma_f32_16x16x32_bf16(pa0, vc[ct * 2 + 0], acc[ct], 0, 0, 0);
            acc[ct] = __builtin_amdgcn_mfma_f32_16x16x32_bf16(pa1, vc[ct * 2 + 1], acc[ct], 0, 0, 0);
            vc[ct * 2 + 0] = *(const bf16x8*)(vb + (size_t)(ch0 + ct * 16 + l16) * NPOS + j0n + g8 * 8);
            vc[ct * 2 + 1] = *(const bf16x8*)(vb + (size_t)(ch0 + ct * 16 + l16) * NPOS + j0n + 32 + g8 * 8);
        }
        __builtin_amdgcn_s_setprio(0);
    }

    acc[0][0] += lrun + mrun;   // keep softmax state live
    float* po = pO + ((size_t)bid * 512 + t) * 32;
    #pragma unroll
    for (int ct = 0; ct < 8; ++ct)
        *(f32x4*)(po + ct * 4) = acc[ct];
}

// ---------------------------------------------------------------------------
// Merge two key-halves (unchanged).
// ---------------------------------------------------------------------------
__global__ __launch_bounds__(256) void merge_kernel(
    const float* __restrict__ pO, const float* __restrict__ pml,
    const float* __restrict__ input, const float* __restrict__ gamma,
    float* __restrict__ out)
{
    const int blk = blockIdx.x;
    const int s = blk >> 2, cq = blk & 3;
    const int t = threadIdx.x;
    const int n = t & 63, sub = t >> 6;
    const int b = s >> 6, tile = s & 63;
    const int i0 = tile * 64;

    const float2 A  = ((const float2*)pml)[(size_t)s * 64 + n];
    const float2 Bv = ((const float2*)pml)[(size_t)(256 + s) * 64 + n];
    float m = fmaxf(A.x, Bv.x);
    float wA = exp2f(A.x - m), wB = exp2f(Bv.x - m);
    float inv = 1.0f / (A.y * wA + Bv.y * wB);
    wA *= inv; wB *= inv;
    const float g = gamma[0];

    #pragma unroll 4
    for (int cc = 0; cc < 16; ++cc) {
        int ch = cq * 64 + sub * 16 + cc;
        size_t pidx = ((size_t)s * 256 + ch) * 64 + n;
        float oA = pO[pidx];
        float oB = pO[pidx + (size_t)4194304];
        size_t gi = ((size_t)b * 256 + ch) * 4096 + i0 + n;
        out[gi] = g * (oA * wA + oB * wB) + input[gi];
    }
}

// ---------------------------------------------------------------------------
extern "C" void kernel_launch(void* const* d_in, const int* in_sizes, int n_in,
                              void* d_out, int out_size, void* d_ws, size_t ws_size,
                              hipStream_t stream) {
    const float* input = (const float*)d_in[0];
    const float* wq    = (const float*)d_in[1];
    const float* bq    = (const float*)d_in[2];
    const float* wk    = (const float*)d_in[3];
    const float* bk    = (const float*)d_in[4];
    const float* wv    = (const float*)d_in[5];
    const float* bv    = (const float*)d_in[6];
    const float* gamma = (const float*)d_in[7];
    float* out = (float*)d_out;

    const size_t qk_elems = (size_t)NB * NPOS * CQK;
    const size_t v_elems  = (size_t)NB * CH * NPOS;
    const size_t w_elems  = 320 * 256;
    size_t base_need = (2 * qk_elems + v_elems + w_elems) * sizeof(u16) + 320 * sizeof(float);
    if (ws_size < base_need) return;

    u16* qw = (u16*)d_ws;
    u16* kw = qw + qk_elems;
    u16* vw = kw + qk_elems;
    u16* wb = vw + v_elems;
    float* bbuf = (float*)(wb + w_elems);

    size_t po_off = (base_need + 255) & ~(size_t)255;
    const size_t pO_elems  = (size_t)2 * 256 * 256 * 64;
    const size_t pml_elems = (size_t)2 * 256 * 64 * 2;
    size_t split_need = po_off + (pO_elems + pml_elems) * sizeof(float);
    bool split = (ws_size >= split_need);

    float* pO  = (float*)((char*)d_ws + po_off);
    float* pml = pO + pO_elems;

    wcvt_kernel<<<dim3(80), dim3(256), 0, stream>>>(wq, bq, wk, bk, wv, bv, wb, bbuf);
    qkv_proj_kernel<<<dim3(NB * (NPOS / 32)), dim3(256), 0, stream>>>(input, wb, bbuf, qw, kw, vw);

    if (split) {
        attn_kernel<true><<<dim3(512), dim3(512), 0, stream>>>(
            qw, kw, vw, input, gamma, out, pO, pml);
        merge_kernel<<<dim3(1024), dim3(256), 0, stream>>>(pO, pml, input, gamma, out);
        // ---- diagnostic ablations (scratch-only, run AFTER merge reads pO) ----
        attn_abl<2><<<dim3(512), dim3(512), 0, stream>>>(qw, kw, vw, pO, pml);  // no producer compute
        attn_abl<3><<<dim3(512), dim3(512), 0, stream>>>(qw, kw, vw, pO, pml);  // no consumer MFMA
        attn_abl<4><<<dim3(512), dim3(512), 0, stream>>>(qw, kw, vw, pO, pml);  // skeleton
        fused_probe<<<dim3(256), dim3(512), 0, stream>>>(qw, kw, vw, pO);       // barrier-free fused
    } else {
        attn_kernel<false><<<dim3(256), dim3(512), 0, stream>>>(
            qw, kw, vw, input, gamma, out, pO, pml);
    }
}

// Round 12
// 75.610 us; speedup vs baseline: 5.9782x; 5.9782x over previous
//
#include <hip/hip_runtime.h>

#define NB    4
#define CH    256
#define CQK   32
#define NPOS  4096
#define KT    64
#define QT    64
#define QTILE 256
#define PARTS 4
#define WPB   16          // windows per block = 4096/PARTS/KT
#define LOG2E 1.4426950408889634f
#define THR2  10.0f       // defer-rescale threshold, log2 units

typedef __attribute__((ext_vector_type(8))) short bf16x8;
typedef __attribute__((ext_vector_type(4))) float f32x4;
typedef unsigned short u16;
typedef unsigned int   u32;

static __device__ __forceinline__ u16 f2bf(float x) {
    union { float f; u32 u; } c; c.f = x;
    u32 u = c.u + 0x7FFFu + ((c.u >> 16) & 1u);
    return (u16)(u >> 16);
}
static __device__ __forceinline__ u32 pack2(float a, float b) {
    return (u32)f2bf(a) | ((u32)f2bf(b) << 16);
}
static __device__ __forceinline__ u32 cvtpk(float a, float b) {
    u32 r;
    asm("v_cvt_pk_bf16_f32 %0, %1, %2" : "=v"(r) : "v"(a), "v"(b));
    return r;
}
static __device__ __forceinline__ float exp2raw(float x) {
    float r;
    asm("v_exp_f32 %0, %1" : "=v"(r) : "v"(x));
    return r;
}

// ---------------------------------------------------------------------------
// W concat + bf16 convert (unchanged).
// ---------------------------------------------------------------------------
__global__ __launch_bounds__(256) void wcvt_kernel(
    const float* __restrict__ wq, const float* __restrict__ bq,
    const float* __restrict__ wk, const float* __restrict__ bk,
    const float* __restrict__ wv, const float* __restrict__ bv,
    u16* __restrict__ wb, float* __restrict__ bb)
{
    int idx = blockIdx.x * 256 + threadIdx.x;
    int e0 = idx * 4;
    const float* src; int off;
    if (e0 < 32 * 256)      { src = wq; off = e0; }
    else if (e0 < 64 * 256) { src = wk; off = e0 - 32 * 256; }
    else                    { src = wv; off = e0 - 64 * 256; }
    float4 v4 = *(const float4*)(src + off);
    *(uint2*)(wb + e0) = make_uint2(pack2(v4.x, v4.y), pack2(v4.z, v4.w));
    if (idx < 320) {
        float b = idx < 32 ? bq[idx] : (idx < 64 ? bk[idx - 32] : bv[idx - 64]);
        bb[idx] = b;
    }
}

// ---------------------------------------------------------------------------
// MFMA QKV projection (unchanged; Q pre-scaled by log2e).
// ---------------------------------------------------------------------------
__global__ __launch_bounds__(256, 1) void qkv_proj_kernel(
    const float* __restrict__ x, const u16* __restrict__ wb, const float* __restrict__ bb,
    u16* __restrict__ qo, u16* __restrict__ ko, u16* __restrict__ vo)
{
    __shared__ u16 ldsx[32][264];
    const int t  = threadIdx.x;
    const int b  = blockIdx.x >> 7;
    const int n0 = (blockIdx.x & 127) * 32;
    const float* xb = x + (size_t)b * CH * NPOS;

    #pragma unroll
    for (int it = 0; it < 4; ++it) {
        int idx = it * 256 + t;
        int cp = idx >> 3;
        int n4 = (idx & 7) * 4;
        int c  = cp * 2;
        float4 a = *(const float4*)(xb + (size_t)c * NPOS + n0 + n4);
        float4 d = *(const float4*)(xb + (size_t)(c + 1) * NPOS + n0 + n4);
        #pragma unroll
        for (int i = 0; i < 4; ++i) {
            int n = n4 + i;
            u32 pv = pack2(((const float*)&a)[i], ((const float*)&d)[i]);
            *(u32*)((char*)ldsx + n * 528 + ((c * 2) ^ ((n & 7) << 4))) = pv;
        }
    }
    __syncthreads();

    const int w = t >> 6, lane = t & 63, g8 = lane >> 4, l16 = lane & 15;

    bf16x8 bf[2][8];
    #pragma unroll
    for (int ns = 0; ns < 2; ++ns) {
        int n = ns * 16 + l16;
        const char* rowp = (const char*)ldsx + n * 528;
        int swz = (n & 7) << 4;
        #pragma unroll
        for (int ks = 0; ks < 8; ++ks)
            bf[ns][ks] = *(const bf16x8*)(rowp + ((ks * 64 + g8 * 16) ^ swz));
    }

    u16* qdst = qo + (size_t)b * NPOS * CQK;
    u16* kdst = ko + (size_t)b * NPOS * CQK;
    u16* vdst = vo + (size_t)b * CH * NPOS;

    bf16x8 afA[8], afB[8];
    #pragma unroll
    for (int ks = 0; ks < 8; ++ks)
        afA[ks] = *(const bf16x8*)(wb + (w * 5 * 16 + l16) * 256 + ks * 32 + g8 * 8);

    #pragma unroll
    for (int j = 0; j < 5; ++j) {
        int ot = w * 5 + j;
        bf16x8* afc = (j & 1) ? afB : afA;
        bf16x8* afn = (j & 1) ? afA : afB;
        if (j + 1 < 5) {
            int otn = ot + 1;
            #pragma unroll
            for (int ks = 0; ks < 8; ++ks)
                afn[ks] = *(const bf16x8*)(wb + (otn * 16 + l16) * 256 + ks * 32 + g8 * 8);
        }
        f32x4 acc[2];
        acc[0] = (f32x4){0.f, 0.f, 0.f, 0.f};
        acc[1] = (f32x4){0.f, 0.f, 0.f, 0.f};
        #pragma unroll
        for (int ks = 0; ks < 8; ++ks) {
            acc[0] = __builtin_amdgcn_mfma_f32_16x16x32_bf16(afc[ks], bf[0][ks], acc[0], 0, 0, 0);
            acc[1] = __builtin_amdgcn_mfma_f32_16x16x32_bf16(afc[ks], bf[1][ks], acc[1], 0, 0, 0);
        }
        float4 bias = *(const float4*)(bb + ot * 16 + g8 * 4);

        if (ot < 4) {
            u16* dst = (ot < 2 ? qdst : kdst);
            float scl = (ot < 2) ? LOG2E : 1.0f;
            int ob = (ot & 1) * 16 + g8 * 4;
            #pragma unroll
            for (int ns = 0; ns < 2; ++ns) {
                int n = n0 + ns * 16 + l16;
                u32 lo = pack2((acc[ns][0] + bias.x) * scl, (acc[ns][1] + bias.y) * scl);
                u32 hi = pack2((acc[ns][2] + bias.z) * scl, (acc[ns][3] + bias.w) * scl);
                *(uint2*)(dst + (size_t)n * CQK + ob) = make_uint2(lo, hi);
            }
        } else {
            int orow = (ot - 4) * 16 + g8 * 4;
            const float* bp = (const float*)&bias;
            #pragma unroll
            for (int r = 0; r < 4; ++r)
                #pragma unroll
                for (int ns = 0; ns < 2; ++ns)
                    vdst[(size_t)(orow + r) * NPOS + n0 + ns * 16 + l16] =
                        f2bf(acc[ns][r] + bp[r]);
        }
    }
}

// ---------------------------------------------------------------------------
// 256-query-tile fused attention, key-split x4.  grid 256, 512 thr = 8 waves.
// block = (part p of 1024 keys) x (batch b) x (qtile of 256 q).
// Wave w: q rows [(w&3)*32, +32) (2 strips) x ch half (w>>2)*128.
// Per window (KT=64): stage V(j+1) global->reg; 8 QK^T mfma (swapped);
// in-wave softmax (defer-rescale, per-lane l); P -> PRIVATE LDS (no barrier);
// PV 32 mfma with V B-frags from block-shared XOR-swizzled dbuf LDS tile
// (B-frag reused x2 strips); staged V -> LDS; ONE raw s_barrier per window.
// Outputs unnormalized bf16 partials + (m,l) per q; merge4 combines.
// LDS: V 2x32KB + P 8x4KB = 96KB.  ~64 AGPR + ~130 VGPR -> 8 waves/CU.
// ---------------------------------------------------------------------------
#define VB_OFF  0
#define P_OFF   65536
#define SMEMSZ  98304

__global__ __launch_bounds__(512, 1) void attn256_kernel(
    const u16* __restrict__ q, const u16* __restrict__ k, const u16* __restrict__ v,
    u16* __restrict__ pOb, float* __restrict__ pml)
{
    __shared__ __align__(16) char smem[SMEMSZ];
    const int t = threadIdx.x;
    const int w = t >> 6;
    const int lane = t & 63;
    const int g8 = lane >> 4;
    const int l16 = lane & 15;

    const int bid  = blockIdx.x;
    const int part = bid >> 6;
    const int bqt  = bid & 63;
    const int b    = bqt >> 4;
    const int qtl  = bqt & 15;
    const int i0   = qtl * QTILE;
    const int kbase = part * (NPOS / PARTS);

    const int sp  = w & 3;          // strip-pair: q rows sp*32..+31
    const int ch0 = (w >> 2) * 128; // ch half

    const u16* qb = q + (size_t)b * NPOS * CQK;
    const u16* kb = k + (size_t)b * NPOS * CQK;
    const u16* vb = v + (size_t)b * CH * NPOS;

    // loop-invariant Q B-frags (2 strips)
    bf16x8 qf[2];
    #pragma unroll
    for (int st = 0; st < 2; ++st)
        qf[st] = *(const bf16x8*)(qb + (size_t)(i0 + sp * 32 + st * 16 + l16) * CQK + g8 * 8);

    // K A-frags window 0
    bf16x8 kc[4];
    #pragma unroll
    for (int nt = 0; nt < 4; ++nt)
        kc[nt] = *(const bf16x8*)(kb + (size_t)(kbase + nt * 16 + l16) * CQK + g8 * 8);

    // stage V window 0 -> buf0 (thread t: ch row t>>1, 64B half t&1)
    const int ch_s = t >> 1;
    const int hf   = t & 1;
    const int vswz = (ch_s & 7) << 4;
    {
        uint4 vst[4];
        #pragma unroll
        for (int j = 0; j < 4; ++j)
            vst[j] = *(const uint4*)(vb + (size_t)ch_s * NPOS + kbase + hf * 32 + j * 8);
        #pragma unroll
        for (int j = 0; j < 4; ++j)
            *(uint4*)(smem + VB_OFF + ch_s * 128 + ((hf * 64 + j * 16) ^ vswz)) = vst[j];
    }
    __syncthreads();

    f32x4 acc[2][8];
    #pragma unroll
    for (int st = 0; st < 2; ++st)
        #pragma unroll
        for (int ct = 0; ct < 8; ++ct)
            acc[st][ct] = (f32x4){0.f, 0.f, 0.f, 0.f};
    float mrun[2] = {-__builtin_inff(), -__builtin_inff()};
    float lrun[2] = {0.f, 0.f};

    char* pw = smem + P_OFF + w * 4096;
    const int pswz = (l16 & 7) << 4;

    for (int jc = 0; jc < WPB; ++jc) {
        const char* vbase = smem + VB_OFF + (jc & 1) * 32768;
        const bool more = (jc + 1 < WPB);

        // stage loads for next window (full-window latency slack)
        uint4 vst[4];
        if (more) {
            int kv = kbase + (jc + 1) * KT;
            #pragma unroll
            for (int j = 0; j < 4; ++j)
                vst[j] = *(const uint4*)(vb + (size_t)ch_s * NPOS + kv + hf * 32 + j * 8);
        }

        // QK^T (swapped): sS[st][nt][r] = S[key nt*16+g8*4+r][q strip-row l16]
        f32x4 z = {0.f, 0.f, 0.f, 0.f};
        f32x4 sS[2][4];
        #pragma unroll
        for (int st = 0; st < 2; ++st)
            #pragma unroll
            for (int nt = 0; nt < 4; ++nt)
                sS[st][nt] = __builtin_amdgcn_mfma_f32_16x16x32_bf16(kc[nt], qf[st], z, 0, 0, 0);

        // in-place K reload (wraps within part; last reload unused)
        {
            int j0n = kbase + ((jc + 1) & (WPB - 1)) * KT;
            #pragma unroll
            for (int nt = 0; nt < 4; ++nt)
                kc[nt] = *(const bf16x8*)(kb + (size_t)(j0n + nt * 16 + l16) * CQK + g8 * 8);
        }

        // softmax per strip: per-lane max over 16 keys; rare rescale
        #pragma unroll
        for (int st = 0; st < 2; ++st) {
            float m0 = fmaxf(fmaxf(sS[st][0][0], sS[st][0][1]), fmaxf(sS[st][0][2], sS[st][0][3]));
            float m1 = fmaxf(fmaxf(sS[st][1][0], sS[st][1][1]), fmaxf(sS[st][1][2], sS[st][1][3]));
            float m2 = fmaxf(fmaxf(sS[st][2][0], sS[st][2][1]), fmaxf(sS[st][2][2], sS[st][2][3]));
            float m3 = fmaxf(fmaxf(sS[st][3][0], sS[st][3][1]), fmaxf(sS[st][3][2], sS[st][3][3]));
            float lmax = fmaxf(fmaxf(m0, m1), fmaxf(m2, m3));
            if (__any(lmax > mrun[st] + THR2)) {     // rare slow path
                float mx = fmaxf(lmax, __shfl_xor(lmax, 16));
                mx = fmaxf(mx, __shfl_xor(mx, 32));
                mx = fmaxf(mx, mrun[st]);
                float sc = exp2raw(mrun[st] - mx);   // exp2(-inf)=0 first time
                mrun[st] = mx;
                lrun[st] *= sc;
                // acc rows are q=g8*4+i; sc lives at lane q=l16
                f32x4 sv;
                #pragma unroll
                for (int i = 0; i < 4; ++i) sv[i] = __shfl(sc, g8 * 4 + i);
                #pragma unroll
                for (int ct = 0; ct < 8; ++ct) acc[st][ct] *= sv;
            }
            // P = exp2(S - m) -> private LDS
            char* prow = pw + st * 2048 + l16 * 128;
            float ls = 0.f;
            #pragma unroll
            for (int nt = 0; nt < 4; ++nt) {
                float a0 = exp2raw(sS[st][nt][0] - mrun[st]);
                float a1 = exp2raw(sS[st][nt][1] - mrun[st]);
                float a2 = exp2raw(sS[st][nt][2] - mrun[st]);
                float a3 = exp2raw(sS[st][nt][3] - mrun[st]);
                ls += (a0 + a1) + (a2 + a3);
                *(uint2*)(prow + ((nt * 32 + g8 * 8) ^ pswz)) =
                    make_uint2(cvtpk(a0, a1), cvtpk(a2, a3));
            }
            lrun[st] += ls;                          // per-lane partial
        }

        // P A-frags back (same wave; compiler inserts lgkmcnt)
        bf16x8 pa[2][2];
        #pragma unroll
        for (int st = 0; st < 2; ++st)
            #pragma unroll
            for (int kc2 = 0; kc2 < 2; ++kc2)
                pa[st][kc2] = *(const bf16x8*)(pw + st * 2048 + l16 * 128 +
                                               ((kc2 * 64 + g8 * 16) ^ pswz));

        // PV: B-frag from shared V tile, reused across 2 strips
        __builtin_amdgcn_s_setprio(1);
        #pragma unroll
        for (int ct = 0; ct < 8; ++ct) {
            int row = ch0 + ct * 16 + l16;
            const char* vrow = vbase + row * 128;
            int rswz = (row & 7) << 4;
            bf16x8 vf0 = *(const bf16x8*)(vrow + ((g8 * 16) ^ rswz));
            bf16x8 vf1 = *(const bf16x8*)(vrow + ((64 + g8 * 16) ^ rswz));
            #pragma unroll
            for (int st = 0; st < 2; ++st) {
                acc[st][ct] = __builtin_amdgcn_mfma_f32_16x16x32_bf16(pa[st][0], vf0, acc[st][ct], 0, 0, 0);
                acc[st][ct] = __builtin_amdgcn_mfma_f32_16x16x32_bf16(pa[st][1], vf1, acc[st][ct], 0, 0, 0);
            }
        }
        __builtin_amdgcn_s_setprio(0);

        // write staged V -> other buffer, then one raw barrier
        if (more) {
            char* vB = smem + VB_OFF + ((jc + 1) & 1) * 32768;
            #pragma unroll
            for (int j = 0; j < 4; ++j)
                *(uint4*)(vB + ch_s * 128 + ((hf * 64 + j * 16) ^ vswz)) = vst[j];
        }
        asm volatile("s_waitcnt lgkmcnt(0)" ::: "memory");
        __builtin_amdgcn_s_barrier();
        asm volatile("" ::: "memory");
    }

    // epilogue: finalize l; write (m,l) once per q; bf16 unnormalized partials
    #pragma unroll
    for (int st = 0; st < 2; ++st) {
        lrun[st] += __shfl_xor(lrun[st], 16);
        lrun[st] += __shfl_xor(lrun[st], 32);
    }
    if ((w >> 2) == 0 && g8 == 0) {
        #pragma unroll
        for (int st = 0; st < 2; ++st) {
            int ql = sp * 32 + st * 16 + l16;
            ((float2*)pml)[((size_t)part * 64 + bqt) * QTILE + ql] =
                make_float2(mrun[st], lrun[st]);
        }
    }
    u16* po = pOb + ((size_t)part * 64 + bqt) * (CH * QTILE);
    #pragma unroll
    for (int st = 0; st < 2; ++st)
        #pragma unroll
        for (int ct = 0; ct < 8; ++ct) {
            int ch = ch0 + ct * 16 + l16;
            int q0 = sp * 32 + st * 16 + g8 * 4;
            f32x4 vvv = acc[st][ct];
            *(uint2*)(po + (size_t)ch * QTILE + q0) =
                make_uint2(cvtpk(vvv[0], vvv[1]), cvtpk(vvv[2], vvv[3]));
        }
}

// ---------------------------------------------------------------------------
// Merge 4 key-parts: out = gamma * (sum_p O_p*w_p) / (sum_p l_p*w_p) + input.
// grid 1024 = (bqt 64) x (ch-group 16); 256 thr = q.
// ---------------------------------------------------------------------------
__global__ __launch_bounds__(256) void merge4_kernel(
    const u16* __restrict__ pOb, const float* __restrict__ pml,
    const float* __restrict__ input, const float* __restrict__ gamma,
    float* __restrict__ out)
{
    const int blk = blockIdx.x;
    const int bqt = blk >> 4;
    const int chg = blk & 15;
    const int qi  = threadIdx.x;
    const int b   = bqt >> 4;
    const int qtl = bqt & 15;

    float mm[PARTS], ll[PARTS];
    float mstar = -__builtin_inff();
    #pragma unroll
    for (int p = 0; p < PARTS; ++p) {
        float2 ml = ((const float2*)pml)[((size_t)p * 64 + bqt) * QTILE + qi];
        mm[p] = ml.x; ll[p] = ml.y;
        mstar = fmaxf(mstar, ml.x);
    }
    float wp[PARTS]; float denom = 0.f;
    #pragma unroll
    for (int p = 0; p < PARTS; ++p) {
        wp[p] = exp2f(mm[p] - mstar);
        denom += ll[p] * wp[p];
    }
    float inv = 1.0f / denom;
    #pragma unroll
    for (int p = 0; p < PARTS; ++p) wp[p] *= inv;
    const float g = gamma[0];

    #pragma unroll 4
    for (int cc = 0; cc < 16; ++cc) {
        int ch = chg * 16 + cc;
        float o = 0.f;
        #pragma unroll
        for (int p = 0; p < PARTS; ++p) {
            u16 raw = pOb[(((size_t)p * 64 + bqt) * CH + ch) * QTILE + qi];
            union { u32 u; float f; } cv; cv.u = (u32)raw << 16;
            o += cv.f * wp[p];
        }
        size_t gi = ((size_t)b * CH + ch) * NPOS + qtl * QTILE + qi;
        out[gi] = g * o + input[gi];
    }
}

// ---------------------------------------------------------------------------
// Fallback attention (R10 <false>: grid 256, full keys, in-kernel epilogue).
// ---------------------------------------------------------------------------
#define FP_OFF   0
#define FSC_OFF  16384
#define FFL_OFF  16896
#define FLL_OFF  16928
#define FSMEM    17184

__global__ __launch_bounds__(512, 2) void attn_fb_kernel(
    const u16* __restrict__ q, const u16* __restrict__ k, const u16* __restrict__ v,
    const float* __restrict__ input, const float* __restrict__ gamma,
    float* __restrict__ out)
{
    __shared__ __align__(16) char smem[FSMEM];
    const int t = threadIdx.x;
    const int w = t >> 6;
    const int lane = t & 63;
    const int g8 = lane >> 4;
    const int l16 = lane & 15;

    constexpr int W = 64;
    const int lb = blockIdx.x & 255;
    const int b = (lb >> 1) & 3;
    const int tile = ((lb >> 3) << 1) | (lb & 1);
    const int i0 = tile * QT;

    const u16* kb = k + (size_t)b * NPOS * CQK;
    const u16* vb = v + (size_t)b * CH * NPOS;

    if (w < 4) {
        const int strip = w;
        const u16* qb = q + (size_t)b * NPOS * CQK;
        bf16x8 qf = *(const bf16x8*)(qb + (size_t)(i0 + strip * 16 + l16) * CQK + g8 * 8);
        float mrun = -__builtin_inff(), lrun = 0.f;
        bf16x8 kc[4];
        #pragma unroll
        for (int nt = 0; nt < 4; ++nt)
            kc[nt] = *(const bf16x8*)(kb + (size_t)(nt * 16 + l16) * CQK + g8 * 8);

        auto pbody = [&](int c) {
            f32x4 z = {0.f, 0.f, 0.f, 0.f};
            f32x4 sS[4];
            #pragma unroll
            for (int nt = 0; nt < 4; ++nt)
                sS[nt] = __builtin_amdgcn_mfma_f32_16x16x32_bf16(kc[nt], qf, z, 0, 0, 0);
            {
                int j0n = ((c + 1) & (W - 1)) * KT;
                #pragma unroll
                for (int nt = 0; nt < 4; ++nt)
                    kc[nt] = *(const bf16x8*)(kb + (size_t)(j0n + nt * 16 + l16) * CQK + g8 * 8);
            }
            float mx4[4];
            #pragma unroll
            for (int nt = 0; nt < 4; ++nt)
                mx4[nt] = fmaxf(fmaxf(sS[nt][0], sS[nt][1]), fmaxf(sS[nt][2], sS[nt][3]));
            float lmax = fmaxf(fmaxf(mx4[0], mx4[1]), fmaxf(mx4[2], mx4[3]));
            const int buf = c & 1;
            float sc = 1.0f;
            u32 flagval = 0u;
            if (__any(lmax > mrun + THR2)) {
                float mxx = fmaxf(lmax, __shfl_xor(lmax, 16));
                mxx = fmaxf(mxx, __shfl_xor(mxx, 32));
                mxx = fmaxf(mxx, mrun);
                sc = exp2raw(mrun - mxx);
                mrun = mxx;
                lrun *= sc;
                flagval = 1u;
            }
            if (g8 == 0)
                *(float*)(smem + FSC_OFF + buf * 256 + (strip * 16 + l16) * 4) = sc;
            float ls = 0.f;
            char* pb = smem + FP_OFF + buf * 8192 + strip * 2048 + l16 * 128;
            int swz = (l16 & 7) << 4;
            #pragma unroll
            for (int nt = 0; nt < 4; ++nt) {
                float a0 = exp2raw(sS[nt][0] - mrun);
                float a1 = exp2raw(sS[nt][1] - mrun);
                float a2 = exp2raw(sS[nt][2] - mrun);
                float a3 = exp2raw(sS[nt][3] - mrun);
                ls += (a0 + a1) + (a2 + a3);
                *(uint2*)(pb + ((nt * 32 + g8 * 8) ^ swz)) =
                    make_uint2(cvtpk(a0, a1), cvtpk(a2, a3));
            }
            lrun += ls;
            if (lane == 0)
                *(u32*)(smem + FFL_OFF + buf * 16 + strip * 4) = flagval;
            asm volatile("s_waitcnt lgkmcnt(0)" ::: "memory");
        };

        pbody(0);
        for (int jc = 0; jc < W; jc += 2) {
            __builtin_amdgcn_s_barrier();
            asm volatile("" ::: "memory");
            pbody(jc + 1);
            __builtin_amdgcn_s_barrier();
            asm volatile("" ::: "memory");
            if (jc + 2 < W) pbody(jc + 2);
        }
        lrun += __shfl_xor(lrun, 16);
        lrun += __shfl_xor(lrun, 32);
        if (g8 == 0)
            *(float*)(smem + FLL_OFF + (strip * 16 + l16) * 4) = lrun;
        __syncthreads();
    } else {
        const int ch0 = (w - 4) * 64;
        bf16x8 vc[8];
        #pragma unroll
        for (int ct = 0; ct < 4; ++ct)
            #pragma unroll
            for (int ks = 0; ks < 2; ++ks)
                vc[ct * 2 + ks] = *(const bf16x8*)(vb + (size_t)(ch0 + ct * 16 + l16) * NPOS
                                                   + ks * 32 + g8 * 8);
        f32x4 acc[4][4];
        #pragma unroll
        for (int mt = 0; mt < 4; ++mt)
            #pragma unroll
            for (int ct = 0; ct < 4; ++ct)
                acc[mt][ct] = (f32x4){0.f, 0.f, 0.f, 0.f};

        auto cbody = [&](int jc) {
            const int buf = jc & 1;
            __builtin_amdgcn_s_barrier();
            asm volatile("" ::: "memory");
            __builtin_amdgcn_sched_barrier(0);
            uint4 fl = *(const uint4*)(smem + FFL_OFF + buf * 16);
            if (fl.x | fl.y | fl.z | fl.w) {
                #pragma unroll
                for (int mt = 0; mt < 4; ++mt) {
                    f32x4 ss = *(const f32x4*)(smem + FSC_OFF + buf * 256 + (mt * 16 + g8 * 4) * 4);
                    #pragma unroll
                    for (int ct = 0; ct < 4; ++ct) acc[mt][ct] *= ss;
                }
            }
            int swz = (l16 & 7) << 4;
            __builtin_amdgcn_s_setprio(1);
            #pragma unroll
            for (int mt = 0; mt < 4; ++mt) {
                const char* pb = smem + FP_OFF + buf * 8192 + mt * 2048 + l16 * 128;
                bf16x8 pa0 = *(const bf16x8*)(pb + ((g8 * 16) ^ swz));
                bf16x8 pa1 = *(const bf16x8*)(pb + ((64 + g8 * 16) ^ swz));
                #pragma unroll
                for (int ct = 0; ct < 4; ++ct) {
                    acc[mt][ct] = __builtin_amdgcn_mfma_f32_16x16x32_bf16(pa0, vc[ct * 2 + 0], acc[mt][ct], 0, 0, 0);
                    acc[mt][ct] = __builtin_amdgcn_mfma_f32_16x16x32_bf16(pa1, vc[ct * 2 + 1], acc[mt][ct], 0, 0, 0);
                }
            }
            __builtin_amdgcn_s_setprio(0);
            {
                int j0n = ((jc + 1) & (W - 1)) * KT;
                #pragma unroll
                for (int ct = 0; ct < 4; ++ct)
                    #pragma unroll
                    for (int ks = 0; ks < 2; ++ks)
                        vc[ct * 2 + ks] = *(const bf16x8*)(vb + (size_t)(ch0 + ct * 16 + l16) * NPOS
                                                           + j0n + ks * 32 + g8 * 8);
            }
        };

        for (int jc = 0; jc < W; ++jc) cbody(jc);
        __syncthreads();
        f32x4 linv[4];
        #pragma unroll
        for (int mt = 0; mt < 4; ++mt) {
            f32x4 lv = *(const f32x4*)(smem + FLL_OFF + (mt * 16 + g8 * 4) * 4);
            f32x4 one = {1.f, 1.f, 1.f, 1.f};
            linv[mt] = one / lv;
        }
        const float gmm = gamma[0];
        const float* inb = input + (size_t)b * CH * NPOS;
        float* ob = out + (size_t)b * CH * NPOS;
        #pragma unroll
        for (int mt = 0; mt < 4; ++mt) {
            #pragma unroll
            for (int ct = 0; ct < 4; ++ct) {
                f32x4 val = acc[mt][ct] * linv[mt];
                int ch = ch0 + ct * 16 + l16;
                size_t gi = (size_t)ch * NPOS + i0 + mt * 16 + g8 * 4;
                float4 in4 = *(const float4*)(inb + gi);
                float4 r4;
                r4.x = gmm * val[0] + in4.x;
                r4.y = gmm * val[1] + in4.y;
                r4.z = gmm * val[2] + in4.z;
                r4.w = gmm * val[3] + in4.w;
                *(float4*)(ob + gi) = r4;
            }
        }
    }
}

// ---------------------------------------------------------------------------
extern "C" void kernel_launch(void* const* d_in, const int* in_sizes, int n_in,
                              void* d_out, int out_size, void* d_ws, size_t ws_size,
                              hipStream_t stream) {
    const float* input = (const float*)d_in[0];
    const float* wq    = (const float*)d_in[1];
    const float* bq    = (const float*)d_in[2];
    const float* wk    = (const float*)d_in[3];
    const float* bk    = (const float*)d_in[4];
    const float* wv    = (const float*)d_in[5];
    const float* bv    = (const float*)d_in[6];
    const float* gamma = (const float*)d_in[7];
    float* out = (float*)d_out;

    const size_t qk_elems = (size_t)NB * NPOS * CQK;
    const size_t v_elems  = (size_t)NB * CH * NPOS;
    const size_t w_elems  = 320 * 256;
    size_t base_need = (2 * qk_elems + v_elems + w_elems) * sizeof(u16) + 320 * sizeof(float);
    if (ws_size < base_need) return;

    u16* qw = (u16*)d_ws;
    u16* kw = qw + qk_elems;
    u16* vw = kw + qk_elems;
    u16* wb = vw + v_elems;
    float* bbuf = (float*)(wb + w_elems);

    size_t po_off = (base_need + 255) & ~(size_t)255;
    const size_t pO_elems  = (size_t)PARTS * 64 * CH * QTILE;      // 16.8M u16 = 32MB
    const size_t pml_elems = (size_t)PARTS * 64 * QTILE * 2;       // f32
    size_t big_need = po_off + pO_elems * sizeof(u16) + pml_elems * sizeof(float);
    bool big = (ws_size >= big_need);

    u16*   pOb = (u16*)((char*)d_ws + po_off);
    float* pml = (float*)(pOb + pO_elems);

    wcvt_kernel<<<dim3(80), dim3(256), 0, stream>>>(wq, bq, wk, bk, wv, bv, wb, bbuf);
    qkv_proj_kernel<<<dim3(NB * (NPOS / 32)), dim3(256), 0, stream>>>(input, wb, bbuf, qw, kw, vw);

    if (big) {
        attn256_kernel<<<dim3(256), dim3(512), 0, stream>>>(qw, kw, vw, pOb, pml);
        merge4_kernel<<<dim3(1024), dim3(256), 0, stream>>>(pOb, pml, input, gamma, out);
    } else {
        attn_fb_kernel<<<dim3(256), dim3(512), 0, stream>>>(qw, kw, vw, input, gamma, out);
    }
}